// Round 18
// baseline (3197.111 us; speedup 1.0000x reference)
//
#include <hip/hip_runtime.h>
#include <hip/hip_cooperative_groups.h>

namespace cg = cooperative_groups;

// Paraformer-large streaming decoder dims (CKV derived at runtime from in_sizes)
constexpr int LAY = 16, HID = 512, FF = 2048, NHD = 4, DKH = 128, KW = 11,
              VOC = 8404, TT = 64, SEQ = 2048, LBN = 256;

// LDS XOR swizzle (proven r13): kills 8-way store conflicts
#define SWZ(row, e) ((e) ^ ((((row) >> 2) & 7) << 2))

// ---------------- diagnostic ----------------
__global__ void diag_k(float* __restrict__ p, float v) { p[threadIdx.x] = v; }

struct CA {
  const float* enc; const float* lfrm; const float* fcache;
  const float* kcache; const float* vcache;
  const float* n1g; const float* n1b; const float* n2g; const float* n2b;
  const float* n3g; const float* n3b; const float* fng; const float* fnb;
  const float* w1; const float* b1; const float* w2; const float* fw;
  const float* qw; const float* qbi; const float* kvw; const float* kvbi;
  const float* ow; const float* obi;
  const float* d3n1g; const float* d3n1b; const float* d3w1; const float* d3b1;
  const float* d3fng; const float* d3fnb; const float* d3w2;
  const float* ang; const float* anb; const float* outw; const float* outb;
  float* lf; float* y1; float* y2; float* y4; float* xb; float* ctx;
  float* rs; float* lg; float* sc;
  float* part; float* partE; float* partN;
  float* out_fsmn; float* out_ids;
  int ckv; int sct; int ncho; long pz_ctx;
};

// ---- split-K reduce + bias/res/relu + LayerNorm (row-per-vb) ----
__device__ void d_redln(const float* __restrict__ P, int N, int nch,
                        const float* __restrict__ bias,
                        const float* __restrict__ res, int relu,
                        const float* __restrict__ g, const float* __restrict__ b,
                        float* __restrict__ out1, float* __restrict__ out2,
                        float* sm) {
  float* buf = sm;
  float* red = sm + 2048;
  const int tid = threadIdx.x;
  for (int m = blockIdx.x; m < 64; m += gridDim.x) {
    float s = 0.f;
    for (int n = tid; n < N; n += 256) {
      const float* p = P + (size_t)m * N + n;
      float v = 0.f;
      for (int c = 0; c < nch; ++c) v += p[(size_t)c * 64 * N];
      if (bias) v += bias[n];
      if (res) v += res[(size_t)m * N + n];
      if (relu) v = fmaxf(v, 0.f);
      if (out1) out1[(size_t)m * N + n] = v;
      buf[n] = v; s += v;
    }
    red[tid] = s; __syncthreads();
    for (int st = 128; st > 0; st >>= 1) { if (tid < st) red[tid] += red[tid + st]; __syncthreads(); }
    const float mean = red[0] / N;
    __syncthreads();
    float vs = 0.f;
    for (int n = tid; n < N; n += 256) { float d = buf[n] - mean; vs += d * d; }
    red[tid] = vs; __syncthreads();
    for (int st = 128; st > 0; st >>= 1) { if (tid < st) red[tid] += red[tid + st]; __syncthreads(); }
    const float inv = rsqrtf(red[0] / N + 1e-5f);
    for (int n = tid; n < N; n += 256)
      out2[(size_t)m * N + n] = (buf[n] - mean) * inv * g[n] + b[n];
    __syncthreads();
  }
}

// ---- gemm32: 64x32-tile split-K partial GEMM ----
__device__ void d_gemm32(const float* __restrict__ A, int lda, long sA,
                         const float* __restrict__ B, int ldb, long sB,
                         int N, int Kd, int nch, int Z,
                         float* __restrict__ part, long pzs, int coff,
                         int aCh, long aChS, float* sm) {
  const int nx = N >> 5;
  const int tot = nx * nch * Z;
  const int tid = threadIdx.x;
  const int l16r = tid >> 4, l16c = tid & 15;
  const int lr = tid >> 3, lc = tid & 7;
  float (*As)[64] = (float(*)[64])sm;
  float (*Bs)[40] = (float(*)[40])(sm + 4096);
  const int fa = (l16c & 7) << 2;
  const int ktiles = Kd >> 6;
  for (int vb = blockIdx.x; vb < tot; vb += gridDim.x) {
    const int bx = vb % nx;
    const int r2 = vb / nx;
    const int chunk = r2 % nch;
    const int z = r2 / nch;
    const float* Az = A + (long)z * sA;
    const float* Bz = B + (long)z * sB;
    const int bn = bx * 32;
    float acc[2][4] = {};
    for (int kt = chunk; kt < ktiles; kt += nch) {
      const int k0 = kt << 6;
      __syncthreads();
#pragma unroll
      for (int i = 0; i < 4; ++i) {
        const int r = l16r + 16 * i;
        const float* ap = Az + (size_t)r * lda + k0 + l16c * 4;
        float4 av = *(const float4*)ap;
        for (int c = 1; c < aCh; ++c) {
          const float4 t2 = *(const float4*)(ap + (size_t)c * aChS);
          av.x += t2.x; av.y += t2.y; av.z += t2.z; av.w += t2.w;
        }
        As[l16c * 4 + 0][r ^ fa] = av.x; As[l16c * 4 + 1][r ^ fa] = av.y;
        As[l16c * 4 + 2][r ^ fa] = av.z; As[l16c * 4 + 3][r ^ fa] = av.w;
      }
#pragma unroll
      for (int i = 0; i < 2; ++i) {
        const int rb = lr + 32 * i;
        const float4 bv = *(const float4*)(Bz + (size_t)(k0 + rb) * ldb + bn + lc * 4);
        *(float4*)(&Bs[rb][lc * 4]) = bv;
      }
      __syncthreads();
#pragma unroll 8
      for (int kk = 0; kk < 64; ++kk) {
        const int fk = ((kk >> 2) & 7) << 2;
        const float2 aa = *(const float2*)(&As[kk][(lr * 2) ^ fk]);
        const float4 bb = *(const float4*)(&Bs[kk][lc * 4]);
        acc[0][0] += aa.x * bb.x; acc[0][1] += aa.x * bb.y; acc[0][2] += aa.x * bb.z; acc[0][3] += aa.x * bb.w;
        acc[1][0] += aa.y * bb.x; acc[1][1] += aa.y * bb.y; acc[1][2] += aa.y * bb.z; acc[1][3] += aa.y * bb.w;
      }
    }
    float* P = part + (size_t)z * pzs + (size_t)(coff + chunk) * 64 * N;
#pragma unroll
    for (int i = 0; i < 2; ++i) {
      const int m = lr * 2 + i;
#pragma unroll
      for (int j = 0; j < 4; ++j) P[(size_t)m * N + bn + lc * 4 + j] = acc[i][j];
    }
    __syncthreads();
  }
}

// ---- FSMN conv + residuals + x_cat + LN3 ----
__device__ void d_fsmnln(const float* __restrict__ y4, const float* __restrict__ lfin,
                         const float* __restrict__ cache, const float* __restrict__ fw,
                         const float* __restrict__ g, const float* __restrict__ b,
                         float* __restrict__ xb, float* __restrict__ xcat,
                         float* __restrict__ y1out, float* sm) {
  float* buf = sm;
  float* red = sm + 512;
  const int tid = threadIdx.x;
  for (int t = blockIdx.x; t < 64; t += gridDim.x) {
    float s = 0.f;
    for (int h = tid; h < HID; h += 256) {
      float conv = 0.f;
#pragma unroll
      for (int k = 0; k < KW; ++k) {
        const int j = t + k;
        const float xcv = (j < KW - 1) ? cache[h * (KW - 1) + j]
                                       : y4[(size_t)(j - (KW - 1)) * HID + h];
        conv += xcv * fw[h * KW + k];
      }
      const float yv = y4[(size_t)t * HID + h];
      const float x = conv + yv + lfin[(size_t)t * HID + h];
      xb[(size_t)t * HID + h] = x;
      buf[h] = x; s += x;
      xcat[h * (KW - 1 + TT) + (KW - 1) + t] = yv;
      if (t == 0) {
        for (int j2 = 0; j2 < KW - 1; ++j2)
          xcat[h * (KW - 1 + TT) + j2] = cache[h * (KW - 1) + j2];
      }
    }
    red[tid] = s; __syncthreads();
    for (int st = 128; st > 0; st >>= 1) { if (tid < st) red[tid] += red[tid + st]; __syncthreads(); }
    const float mean = red[0] / HID;
    __syncthreads();
    float vs = 0.f;
    for (int h = tid; h < HID; h += 256) { float d = buf[h] - mean; vs += d * d; }
    red[tid] = vs; __syncthreads();
    for (int st = 128; st > 0; st >>= 1) { if (tid < st) red[tid] += red[tid + st]; __syncthreads(); }
    const float inv = rsqrtf(red[0] / HID + 1e-5f);
    for (int h = tid; h < HID; h += 256)
      y1out[(size_t)t * HID + h] = (buf[h] - mean) * inv * g[h] + b[h];
    __syncthreads();
  }
}

// ---- attn1: qp (NT vs Wk) + scores-old (NN vs kcache) ----
__device__ void d_attn1(const float* __restrict__ qpart, const float* __restrict__ qbi_l,
                        const float* __restrict__ Wkv, const float* __restrict__ kcl,
                        float* __restrict__ qp, float* __restrict__ sc,
                        int ckv, int sct, float* sm) {
  const int nx = 8 + ckv / 64;
  const int tot = nx * NHD;
  const int tid = threadIdx.x;
  const int lr = tid >> 4, lc = tid & 15;
  float (*As)[64] = (float(*)[64])sm;
  float (*Bs)[64] = (float(*)[64])(sm + 4096);
  const int fa = (lc & 7) << 2;
  for (int vb = blockIdx.x; vb < tot; vb += gridDim.x) {
    const int bxx = vb % nx;
    const int h = vb / nx;
    const bool isQp = bxx < 8;
    const int bn = (isQp ? bxx : bxx - 8) * 64;
    float acc[4][4] = {};
    for (int k0 = 0; k0 < DKH; k0 += 64) {
      __syncthreads();
#pragma unroll
      for (int i = 0; i < 4; ++i) {
        const int r = lr + 16 * i;
        const float* ap = qpart + (size_t)r * HID + h * DKH + k0 + lc * 4;
        float4 av = *(const float4*)ap;
        for (int c = 1; c < 8; ++c) {
          const float4 t2 = *(const float4*)(ap + (size_t)c * 64 * HID);
          av.x += t2.x; av.y += t2.y; av.z += t2.z; av.w += t2.w;
        }
        const float4 bb = *(const float4*)(qbi_l + h * DKH + k0 + lc * 4);
        av.x += bb.x; av.y += bb.y; av.z += bb.z; av.w += bb.w;
        As[lc * 4 + 0][r ^ fa] = av.x; As[lc * 4 + 1][r ^ fa] = av.y;
        As[lc * 4 + 2][r ^ fa] = av.z; As[lc * 4 + 3][r ^ fa] = av.w;
        if (isQp) {
          const float4 bv = *(const float4*)(Wkv + (size_t)(bn + r) * (2 * HID) + h * DKH + k0 + lc * 4);
          Bs[lc * 4 + 0][r ^ fa] = bv.x; Bs[lc * 4 + 1][r ^ fa] = bv.y;
          Bs[lc * 4 + 2][r ^ fa] = bv.z; Bs[lc * 4 + 3][r ^ fa] = bv.w;
        } else {
          const float4 bv = *(const float4*)(kcl + ((size_t)h * DKH + k0 + r) * ckv + bn + lc * 4);
          *(float4*)(&Bs[r][SWZ(r, lc * 4)]) = bv;
        }
      }
      __syncthreads();
#pragma unroll 8
      for (int kk = 0; kk < 64; ++kk) {
        const int fk = ((kk >> 2) & 7) << 2;
        const float4 a = *(const float4*)(&As[kk][(lr * 4) ^ fk]);
        const float4 b = *(const float4*)(&Bs[kk][(lc * 4) ^ fk]);
        acc[0][0] += a.x * b.x; acc[0][1] += a.x * b.y; acc[0][2] += a.x * b.z; acc[0][3] += a.x * b.w;
        acc[1][0] += a.y * b.x; acc[1][1] += a.y * b.y; acc[1][2] += a.y * b.z; acc[1][3] += a.y * b.w;
        acc[2][0] += a.z * b.x; acc[2][1] += a.z * b.y; acc[2][2] += a.z * b.z; acc[2][3] += a.z * b.w;
        acc[3][0] += a.w * b.x; acc[3][1] += a.w * b.y; acc[3][2] += a.w * b.z; acc[3][3] += a.w * b.w;
      }
    }
    if (isQp) {
      float* C = qp + (size_t)h * TT * HID;
#pragma unroll
      for (int i = 0; i < 4; ++i)
#pragma unroll
        for (int j = 0; j < 4; ++j)
          C[(size_t)(lr * 4 + i) * HID + bn + lc * 4 + j] = acc[i][j];
    } else {
      float* C = sc + (size_t)h * TT * sct;
#pragma unroll
      for (int i = 0; i < 4; ++i)
#pragma unroll
        for (int j = 0; j < 4; ++j)
          C[(size_t)(lr * 4 + i) * sct + bn + lc * 4 + j] = acc[i][j];
    }
    __syncthreads();
  }
}

// ---- scores-new = qp @ enc^T, splitK2 (chunk0->sc, chunk1->partN) ----
__device__ void d_scnew(const float* __restrict__ qp, const float* __restrict__ enc,
                        float* __restrict__ sc, float* __restrict__ partN,
                        int ckv, int sct, float* sm) {
  const int tot = 32 * 2 * NHD;
  const int tid = threadIdx.x;
  const int lr = tid >> 4, lc = tid & 15;
  float (*As)[64] = (float(*)[64])sm;
  float (*Bs)[64] = (float(*)[64])(sm + 4096);
  const int fa = (lc & 7) << 2;
  const long TH = (long)TT * HID;
  const long TS = (long)TT * sct;
  for (int vb = blockIdx.x; vb < tot; vb += gridDim.x) {
    const int bxx = vb & 31;
    const int r2 = vb >> 5;
    const int chunk = r2 & 1;
    const int z = r2 >> 1;
    const float* A = qp + (long)z * TH;
    const int bn = bxx * 64;
    float acc[4][4] = {};
    for (int kt = chunk; kt < 8; kt += 2) {
      const int k0 = kt << 6;
      __syncthreads();
#pragma unroll
      for (int i = 0; i < 4; ++i) {
        const int r = lr + 16 * i;
        const float4 av = *(const float4*)(A + (size_t)r * HID + k0 + lc * 4);
        As[lc * 4 + 0][r ^ fa] = av.x; As[lc * 4 + 1][r ^ fa] = av.y;
        As[lc * 4 + 2][r ^ fa] = av.z; As[lc * 4 + 3][r ^ fa] = av.w;
        const float4 bv = *(const float4*)(enc + (size_t)(bn + r) * HID + k0 + lc * 4);
        Bs[lc * 4 + 0][r ^ fa] = bv.x; Bs[lc * 4 + 1][r ^ fa] = bv.y;
        Bs[lc * 4 + 2][r ^ fa] = bv.z; Bs[lc * 4 + 3][r ^ fa] = bv.w;
      }
      __syncthreads();
#pragma unroll 8
      for (int kk = 0; kk < 64; ++kk) {
        const int fk = ((kk >> 2) & 7) << 2;
        const float4 a = *(const float4*)(&As[kk][(lr * 4) ^ fk]);
        const float4 b = *(const float4*)(&Bs[kk][(lc * 4) ^ fk]);
        acc[0][0] += a.x * b.x; acc[0][1] += a.x * b.y; acc[0][2] += a.x * b.z; acc[0][3] += a.x * b.w;
        acc[1][0] += a.y * b.x; acc[1][1] += a.y * b.y; acc[1][2] += a.y * b.z; acc[1][3] += a.y * b.w;
        acc[2][0] += a.z * b.x; acc[2][1] += a.z * b.y; acc[2][2] += a.z * b.z; acc[2][3] += a.z * b.w;
        acc[3][0] += a.w * b.x; acc[3][1] += a.w * b.y; acc[3][2] += a.w * b.z; acc[3][3] += a.w * b.w;
      }
    }
    if (chunk == 0) {
      float* C = sc + ckv + (long)z * TS;
#pragma unroll
      for (int i = 0; i < 4; ++i)
#pragma unroll
        for (int j = 0; j < 4; ++j)
          C[(size_t)(lr * 4 + i) * sct + bn + lc * 4 + j] = acc[i][j];
    } else {
      float* P = partN + (size_t)z * (64L * SEQ);
#pragma unroll
      for (int i = 0; i < 4; ++i)
#pragma unroll
        for (int j = 0; j < 4; ++j)
          P[(size_t)(lr * 4 + i) * SEQ + bn + lc * 4 + j] = acc[i][j];
    }
    __syncthreads();
  }
}

// ---- softmax with fused qc-dot + partN sum ----
__device__ void d_softmax(float* __restrict__ sc, float* __restrict__ rs,
                          const float* __restrict__ qpart, const float* __restrict__ qbi_l,
                          const float* __restrict__ kb, const float* __restrict__ partN,
                          int cols, int newStart, float alpha, float* sm) {
  float* srow = sm;
  float* red = sm + 8192;
  const int tid = threadIdx.x;
  for (int row = blockIdx.x; row < NHD * TT; row += gridDim.x) {
    const int h = row >> 6, t = row & 63;
    float* scr = sc + (size_t)row * cols;
    const float* pn = partN + (size_t)h * 64 * SEQ + (size_t)t * SEQ;
    float qv = 0.f;
    if (tid < DKH) {
      const float* qp0 = qpart + (size_t)t * HID + h * DKH + tid;
      float q = qp0[0];
      for (int c = 1; c < 8; ++c) q += qp0[(size_t)c * 64 * HID];
      q += qbi_l[h * DKH + tid];
      qv = q * kb[h * DKH + tid];
    }
    red[tid] = qv; __syncthreads();
    for (int st = 64; st > 0; st >>= 1) { if (tid < st) red[tid] += red[tid + st]; __syncthreads(); }
    const float qcv = red[0];
    __syncthreads();
    float m = -3.4e38f;
    for (int c = tid; c < cols; c += 256) {
      float v = scr[c];
      if (c >= newStart) v += pn[c - newStart] + qcv;
      v *= alpha;
      srow[c] = v; m = fmaxf(m, v);
    }
    red[tid] = m; __syncthreads();
    for (int st = 128; st > 0; st >>= 1) { if (tid < st) red[tid] = fmaxf(red[tid], red[tid + st]); __syncthreads(); }
    m = red[0]; __syncthreads();
    float s = 0.f;
    for (int c = tid; c < cols; c += 256) {
      const float e = __expf(srow[c] - m);
      srow[c] = e; s += e;
    }
    red[tid] = s; __syncthreads();
    for (int st = 128; st > 0; st >>= 1) { if (tid < st) red[tid] += red[tid + st]; __syncthreads(); }
    const float inv = 1.f / red[0];
    float ns = 0.f;
    for (int c = tid; c < cols; c += 256) {
      const float p = srow[c] * inv; scr[c] = p;
      if (c >= newStart) ns += p;
    }
    __syncthreads();
    red[tid] = ns; __syncthreads();
    for (int st = 128; st > 0; st >>= 1) { if (tid < st) red[tid] += red[tid + st]; __syncthreads(); }
    if (tid == 0) rs[row] = red[0];
    __syncthreads();
  }
}

// ---- attn2: ctx-old (split ncho) + ctxE (split 8) partials ----
__device__ void d_attn2(const float* __restrict__ sc, const float* __restrict__ vcl,
                        const float* __restrict__ enc,
                        float* __restrict__ part, float* __restrict__ partE,
                        int ckv, int sct, int ncho, long pzc, float* sm) {
  const int tot = 10 * 8 * NHD;
  const int tid = threadIdx.x;
  const int lr = tid >> 4, lc = tid & 15;
  float (*As)[64] = (float(*)[64])sm;
  float (*Bs)[64] = (float(*)[64])(sm + 4096);
  const int fa = (lc & 7) << 2;
  for (int vb = blockIdx.x; vb < tot; vb += gridDim.x) {
    const int bxx = vb % 10;
    const int r2 = vb / 10;
    const int by = r2 % 8;
    const int h = r2 / 8;
    const bool isOld = bxx < 2;
    if (isOld && by >= ncho) continue;
    const float* A;
    const float* Bb;
    int lda, ldb, N, ktiles, nch, bn;
    float* P;
    if (isOld) {
      A = sc + (size_t)h * TT * sct;  lda = sct;
      Bb = vcl + (size_t)h * ckv * DKH; ldb = DKH;
      N = DKH; ktiles = ckv >> 6; nch = ncho; bn = bxx * 64;
      P = part + (size_t)h * pzc + (size_t)by * 64 * DKH;
    } else {
      A = sc + ckv + (size_t)h * TT * sct; lda = sct;
      Bb = enc; ldb = HID;
      N = HID; ktiles = SEQ >> 6; nch = 8; bn = (bxx - 2) * 64;
      P = partE + (size_t)h * (8L * 64 * HID) + (size_t)by * 64 * HID;
    }
    float acc[4][4] = {};
    for (int kt = by; kt < ktiles; kt += nch) {
      const int k0 = kt << 6;
      __syncthreads();
#pragma unroll
      for (int i = 0; i < 4; ++i) {
        const int r = lr + 16 * i;
        const float4 av = *(const float4*)(A + (size_t)r * lda + k0 + lc * 4);
        As[lc * 4 + 0][r ^ fa] = av.x; As[lc * 4 + 1][r ^ fa] = av.y;
        As[lc * 4 + 2][r ^ fa] = av.z; As[lc * 4 + 3][r ^ fa] = av.w;
        const float4 bv = *(const float4*)(Bb + (size_t)(k0 + r) * ldb + bn + lc * 4);
        *(float4*)(&Bs[r][SWZ(r, lc * 4)]) = bv;
      }
      __syncthreads();
#pragma unroll 8
      for (int kk = 0; kk < 64; ++kk) {
        const int fk = ((kk >> 2) & 7) << 2;
        const float4 a = *(const float4*)(&As[kk][(lr * 4) ^ fk]);
        const float4 b = *(const float4*)(&Bs[kk][(lc * 4) ^ fk]);
        acc[0][0] += a.x * b.x; acc[0][1] += a.x * b.y; acc[0][2] += a.x * b.z; acc[0][3] += a.x * b.w;
        acc[1][0] += a.y * b.x; acc[1][1] += a.y * b.y; acc[1][2] += a.y * b.z; acc[1][3] += a.y * b.w;
        acc[2][0] += a.z * b.x; acc[2][1] += a.z * b.y; acc[2][2] += a.z * b.z; acc[2][3] += a.z * b.w;
        acc[3][0] += a.w * b.x; acc[3][1] += a.w * b.y; acc[3][2] += a.w * b.z; acc[3][3] += a.w * b.w;
      }
    }
#pragma unroll
    for (int i = 0; i < 4; ++i)
#pragma unroll
      for (int j = 0; j < 4; ++j)
        P[(size_t)(lr * 4 + i) * N + bn + lc * 4 + j] = acc[i][j];
    __syncthreads();
  }
}

// ---- ctx reduce (+ rs*bias_v) ----
__device__ void d_red(const float* __restrict__ P, float* __restrict__ out,
                      int N, int nch, long pzs, int outld, int zoff,
                      const float* __restrict__ rsv, const float* __restrict__ bvv,
                      int total) {
  for (int idx = blockIdx.x * 256 + threadIdx.x; idx < total; idx += gridDim.x * 256) {
    const int z = idx / (64 * N);
    const int rem = idx - z * 64 * N;
    const int t = rem / N;
    const int n = rem - t * N;
    const float* p = P + (size_t)z * pzs + (size_t)t * N + n;
    float s = 0.f;
    for (int c = 0; c < nch; ++c) s += p[(size_t)c * 64 * N];
    const int oc = z * zoff + n;
    s += rsv[z * 64 + t] * bvv[oc];
    out[(size_t)t * outld + oc] = s;
  }
}

// ---- vocab gemm ----
__device__ void d_vocab(const float* __restrict__ A, const float* __restrict__ B,
                        float* __restrict__ C, const float* __restrict__ bias,
                        float* sm) {
  const int tot = (VOC + 63) / 64;
  const int tid = threadIdx.x;
  const int lr = tid >> 4, lc = tid & 15;
  float (*As)[64] = (float(*)[64])sm;
  float (*Bs)[64] = (float(*)[64])(sm + 4096);
  const int fa = (lc & 7) << 2;
  for (int vb = blockIdx.x; vb < tot; vb += gridDim.x) {
    const int bn = vb * 64;
    float acc[4][4] = {};
    for (int k0 = 0; k0 < HID; k0 += 64) {
      __syncthreads();
#pragma unroll
      for (int i = 0; i < 4; ++i) {
        const int r = lr + 16 * i;
        const float4 av = *(const float4*)(A + (size_t)r * HID + k0 + lc * 4);
        As[lc * 4 + 0][r ^ fa] = av.x; As[lc * 4 + 1][r ^ fa] = av.y;
        As[lc * 4 + 2][r ^ fa] = av.z; As[lc * 4 + 3][r ^ fa] = av.w;
        const int n = bn + lc * 4;
        const float* bp = B + (size_t)(k0 + r) * VOC + n;
        float4 bv;
        if (n + 3 < VOC) bv = *(const float4*)bp;
        else {
          bv.x = (n + 0 < VOC) ? bp[0] : 0.f;
          bv.y = (n + 1 < VOC) ? bp[1] : 0.f;
          bv.z = (n + 2 < VOC) ? bp[2] : 0.f;
          bv.w = (n + 3 < VOC) ? bp[3] : 0.f;
        }
        *(float4*)(&Bs[r][SWZ(r, lc * 4)]) = bv;
      }
      __syncthreads();
#pragma unroll 8
      for (int kk = 0; kk < 64; ++kk) {
        const int fk = ((kk >> 2) & 7) << 2;
        const float4 a = *(const float4*)(&As[kk][(lr * 4) ^ fk]);
        const float4 b = *(const float4*)(&Bs[kk][(lc * 4) ^ fk]);
        acc[0][0] += a.x * b.x; acc[0][1] += a.x * b.y; acc[0][2] += a.x * b.z; acc[0][3] += a.x * b.w;
        acc[1][0] += a.y * b.x; acc[1][1] += a.y * b.y; acc[1][2] += a.y * b.z; acc[1][3] += a.y * b.w;
        acc[2][0] += a.z * b.x; acc[2][1] += a.z * b.y; acc[2][2] += a.z * b.z; acc[2][3] += a.z * b.w;
        acc[3][0] += a.w * b.x; acc[3][1] += a.w * b.y; acc[3][2] += a.w * b.z; acc[3][3] += a.w * b.w;
      }
    }
#pragma unroll
    for (int i = 0; i < 4; ++i) {
      const int m = lr * 4 + i;
#pragma unroll
      for (int j = 0; j < 4; ++j) {
        const int n = bn + lc * 4 + j;
        if (n < VOC) C[(size_t)m * VOC + n] = acc[i][j] + bias[n];
      }
    }
    __syncthreads();
  }
}

// ---- argmax (first-max tie-break) ----
__device__ void d_argmax(const float* __restrict__ lg, float* __restrict__ out,
                         float* sm) {
  float* vs = sm;
  int* ix = (int*)(sm + 256);
  const int tid = threadIdx.x;
  for (int row = blockIdx.x; row < TT; row += gridDim.x) {
    const float* lr_ = lg + (size_t)row * VOC;
    float bm = -3.4e38f;
    int bi = 0;
    for (int c = tid; c < VOC; c += 256) { float v = lr_[c]; if (v > bm) { bm = v; bi = c; } }
    vs[tid] = bm; ix[tid] = bi; __syncthreads();
    for (int st = 128; st > 0; st >>= 1) {
      if (tid < st) {
        if (vs[tid + st] > vs[tid] || (vs[tid + st] == vs[tid] && ix[tid + st] < ix[tid])) {
          vs[tid] = vs[tid + st]; ix[tid] = ix[tid + st];
        }
      }
      __syncthreads();
    }
    if (tid == 0) out[row] = (float)ix[0];
    __syncthreads();
  }
}

// __launch_bounds__(256, 2): cap VGPR <= 256 so >= 2 blocks/CU are resident
// (grid is additionally clamped by a host-side occupancy query).
__global__ __launch_bounds__(256, 2) void chain_k(CA a) {
  __shared__ float sm[8448];
  cg::grid_group grid = cg::this_grid();
  const float alpha = 0.08838834764831845f;

  d_redln(a.lfrm, HID, 1, nullptr, nullptr, 0, a.n1g, a.n1b, a.lf, a.y1, sm);
  grid.sync();

  for (int l = 0; l < LAY; ++l) {
    const float* Wkv = a.kvw + (size_t)l * HID * 2 * HID;
    const float* Bkv = a.kvbi + (size_t)l * 2 * HID;
    const float* qbi_l = a.qbi + (size_t)l * HID;
    d_gemm32(a.y1, HID, 0, a.w1 + (size_t)l * HID * FF, FF, 0, FF, HID, 8, 1,
             a.part, 0, 0, 1, 0, sm);
    grid.sync();
    d_redln(a.part, FF, 8, a.b1 + (size_t)l * FF, nullptr, 1,
            a.fng + (size_t)l * FF, a.fnb + (size_t)l * FF, nullptr, a.y2, sm);
    grid.sync();
    d_gemm32(a.y2, FF, 0, a.w2 + (size_t)l * FF * HID, HID, 0, HID, FF, 32, 1,
             a.part, 0, 0, 1, 0, sm);
    grid.sync();
    d_redln(a.part, HID, 32, nullptr, nullptr, 0,
            a.n2g + l * HID, a.n2b + l * HID, nullptr, a.y4, sm);
    grid.sync();
    d_fsmnln(a.y4, a.lf, a.fcache + (size_t)l * HID * (KW - 1),
             a.fw + (size_t)l * HID * KW, a.n3g + l * HID, a.n3b + l * HID,
             a.xb, a.out_fsmn + (size_t)l * HID * (KW - 1 + TT), a.y1, sm);
    grid.sync();
    d_gemm32(a.y1, HID, 0, a.qw + (size_t)l * HID * HID, HID, 0, HID, HID, 8, 1,
             a.part, 0, 0, 1, 0, sm);
    grid.sync();
    d_attn1(a.part, qbi_l, Wkv, a.kcache + (size_t)l * NHD * DKH * a.ckv,
            a.ctx, a.sc, a.ckv, a.sct, sm);
    grid.sync();
    d_scnew(a.ctx, a.enc, a.sc, a.partN, a.ckv, a.sct, sm);
    grid.sync();
    d_softmax(a.sc, a.rs, a.part, qbi_l, Bkv, a.partN, a.sct, a.ckv, alpha, sm);
    grid.sync();
    d_attn2(a.sc, a.vcache + (size_t)l * NHD * a.ckv * DKH, a.enc,
            a.part, a.partE, a.ckv, a.sct, a.ncho, a.pz_ctx, sm);
    grid.sync();
    d_gemm32(a.partE, HID, 8L * 64 * HID, Wkv + HID, 2 * HID, DKH,
             DKH, HID, 4, NHD, a.part, a.pz_ctx, a.ncho, 8, 64L * HID, sm);
    grid.sync();
    d_red(a.part, a.y2, DKH, a.ncho + 4, a.pz_ctx, HID, DKH,
          a.rs, Bkv + HID, NHD * TT * DKH);
    grid.sync();
    d_gemm32(a.y2, HID, 0, a.ow + (size_t)l * HID * HID, HID, 0, HID, HID, 8, 1,
             a.part, 0, 0, 1, 0, sm);
    grid.sync();
    const float* ng = (l + 1 < LAY) ? a.n1g + (l + 1) * HID : a.d3n1g;
    const float* nb = (l + 1 < LAY) ? a.n1b + (l + 1) * HID : a.d3n1b;
    d_redln(a.part, HID, 8, a.obi + (size_t)l * HID, a.xb, 0, ng, nb, a.lf, a.y1, sm);
    grid.sync();
  }

  d_gemm32(a.y1, HID, 0, a.d3w1, FF, 0, FF, HID, 8, 1, a.part, 0, 0, 1, 0, sm);
  grid.sync();
  d_redln(a.part, FF, 8, a.d3b1, nullptr, 1, a.d3fng, a.d3fnb, nullptr, a.y2, sm);
  grid.sync();
  d_gemm32(a.y2, FF, 0, a.d3w2, HID, 0, HID, FF, 32, 1, a.part, 0, 0, 1, 0, sm);
  grid.sync();
  d_redln(a.part, HID, 32, nullptr, nullptr, 0, a.ang, a.anb, nullptr, a.y4, sm);
  grid.sync();
  d_vocab(a.y4, a.outw, a.lg, a.outb, sm);
  grid.sync();
  d_argmax(a.lg, a.out_ids, sm);
}

// ============================================================================
// Fallback path kernels (r16-equivalent, proven ~2944 us)
// ============================================================================
__global__ __launch_bounds__(256) void redln_k(
    const float* __restrict__ P, int N, int nch,
    const float* __restrict__ bias, const float* __restrict__ res, int relu,
    const float* __restrict__ g, const float* __restrict__ b,
    float* __restrict__ out1, float* __restrict__ out2) {
  __shared__ float sm[2304];
  d_redln(P, N, nch, bias, res, relu, g, b, out1, out2, sm);
}

__global__ __launch_bounds__(256) void gemm32_k(
    const float* __restrict__ A, int lda, long sA,
    const float* __restrict__ B, int ldb, long sB,
    int N, int Kd, int nch, int Z,
    float* __restrict__ part, long pzs, int coff, int aCh, long aChS) {
  __shared__ float sm[6656];
  d_gemm32(A, lda, sA, B, ldb, sB, N, Kd, nch, Z, part, pzs, coff, aCh, aChS, sm);
}

__global__ __launch_bounds__(256) void fsmnln_k(
    const float* __restrict__ y4, const float* __restrict__ lfin,
    const float* __restrict__ cache, const float* __restrict__ fw,
    const float* __restrict__ g, const float* __restrict__ b,
    float* __restrict__ xb, float* __restrict__ xcat, float* __restrict__ y1out) {
  __shared__ float sm[768];
  d_fsmnln(y4, lfin, cache, fw, g, b, xb, xcat, y1out, sm);
}

__global__ __launch_bounds__(256) void attn1_k(
    const float* __restrict__ qpart, const float* __restrict__ qbi_l,
    const float* __restrict__ Wkv, const float* __restrict__ kcl,
    float* __restrict__ qp, float* __restrict__ sc, int ckv, int sct) {
  __shared__ float sm[8192];
  d_attn1(qpart, qbi_l, Wkv, kcl, qp, sc, ckv, sct, sm);
}

__global__ __launch_bounds__(256) void scnew_k(
    const float* __restrict__ qp, const float* __restrict__ enc,
    float* __restrict__ sc, float* __restrict__ partN, int ckv, int sct) {
  __shared__ float sm[8192];
  d_scnew(qp, enc, sc, partN, ckv, sct, sm);
}

__global__ __launch_bounds__(256) void softmax_k(
    float* __restrict__ sc, float* __restrict__ rs,
    const float* __restrict__ qpart, const float* __restrict__ qbi_l,
    const float* __restrict__ kb, const float* __restrict__ partN,
    int cols, int newStart, float alpha) {
  __shared__ float sm[8448];
  d_softmax(sc, rs, qpart, qbi_l, kb, partN, cols, newStart, alpha, sm);
}

__global__ __launch_bounds__(256) void attn2_k(
    const float* __restrict__ sc, const float* __restrict__ vcl,
    const float* __restrict__ enc, float* __restrict__ part,
    float* __restrict__ partE, int ckv, int sct, int ncho, long pzc) {
  __shared__ float sm[8192];
  d_attn2(sc, vcl, enc, part, partE, ckv, sct, ncho, pzc, sm);
}

__global__ __launch_bounds__(256) void red_k(
    const float* __restrict__ P, float* __restrict__ out,
    int N, int nch, long pzs, int outld, int zoff,
    const float* __restrict__ rsv, const float* __restrict__ bvv, int total) {
  d_red(P, out, N, nch, pzs, outld, zoff, rsv, bvv, total);
}

__global__ __launch_bounds__(256) void vocab_k(
    const float* __restrict__ A, const float* __restrict__ B,
    float* __restrict__ C, const float* __restrict__ bias) {
  __shared__ float sm[8192];
  d_vocab(A, B, C, bias, sm);
}

__global__ __launch_bounds__(256) void argmax_k(const float* __restrict__ lg,
                                                float* __restrict__ out) {
  __shared__ float sm[512];
  d_argmax(lg, out, sm);
}

// ---- save_keys / save_values (always a trailing normal launch) ----
__global__ __launch_bounds__(256) void kvsave_k(const float* __restrict__ enc,
                                                const float* __restrict__ kvw,
                                                const float* __restrict__ kvb,
                                                float* __restrict__ keys,
                                                float* __restrict__ vals) {
  __shared__ float As[64][64];
  __shared__ float Bs[64][64];
  const int tid = threadIdx.x;
  const int lr = tid >> 4, lc = tid & 15;
  const int bn = blockIdx.x * 64, bm = blockIdx.y * 64;
  const int l = blockIdx.z;
  const float* W = kvw + (size_t)l * HID * 2 * HID;
  const int fa = (lc & 7) << 2;
  float acc[4][4] = {};
  for (int k0 = 0; k0 < HID; k0 += 64) {
    __syncthreads();
#pragma unroll
    for (int i = 0; i < 4; ++i) {
      const int r = lr + 16 * i;
      const float4 av =
          *(const float4*)(enc + (size_t)(SEQ - LBN + bm + r) * HID + k0 + lc * 4);
      As[lc * 4 + 0][r ^ fa] = av.x; As[lc * 4 + 1][r ^ fa] = av.y;
      As[lc * 4 + 2][r ^ fa] = av.z; As[lc * 4 + 3][r ^ fa] = av.w;
      const float4 bv = *(const float4*)(W + (size_t)(k0 + r) * (2 * HID) + bn + lc * 4);
      *(float4*)(&Bs[r][SWZ(r, lc * 4)]) = bv;
    }
    __syncthreads();
#pragma unroll 8
    for (int kk = 0; kk < 64; ++kk) {
      const int fk = ((kk >> 2) & 7) << 2;
      const float4 a = *(const float4*)(&As[kk][(lr * 4) ^ fk]);
      const float4 b = *(const float4*)(&Bs[kk][(lc * 4) ^ fk]);
      acc[0][0] += a.x * b.x; acc[0][1] += a.x * b.y; acc[0][2] += a.x * b.z; acc[0][3] += a.x * b.w;
      acc[1][0] += a.y * b.x; acc[1][1] += a.y * b.y; acc[1][2] += a.y * b.z; acc[1][3] += a.y * b.w;
      acc[2][0] += a.z * b.x; acc[2][1] += a.z * b.y; acc[2][2] += a.z * b.z; acc[2][3] += a.z * b.w;
      acc[3][0] += a.w * b.x; acc[3][1] += a.w * b.y; acc[3][2] += a.w * b.z; acc[3][3] += a.w * b.w;
    }
  }
#pragma unroll
  for (int i = 0; i < 4; ++i) {
    const int m = bm + lr * 4 + i;
#pragma unroll
    for (int j = 0; j < 4; ++j) {
      const int n = bn + lc * 4 + j;
      const float v = acc[i][j] + kvb[(size_t)l * 2 * HID + n];
      if (n < 512) {
        const int h = n >> 7, d = n & 127;
        keys[(((size_t)l * NHD + h) * DKH + d) * LBN + m] = v;
      } else {
        const int c = n - 512, h = c >> 7, d = c & 127;
        vals[(((size_t)l * NHD + h) * LBN + m) * DKH + d] = v;
      }
    }
  }
}

extern "C" void kernel_launch(void* const* d_in, const int* in_sizes, int n_in,
                              void* d_out, int out_size, void* d_ws, size_t ws_size,
                              hipStream_t stream) {
  static const int EXPECT[34] = {
      1048576, 32768, 81920, -1, -1,
      8192, 8192, 8192, 8192, 8192, 8192,
      32768, 32768,
      16777216, 32768, 16777216, 90112,
      4194304, 8192, 8388608, 16384, 4194304, 8192,
      512, 512, 1048576, 2048, 2048, 2048, 1048576,
      512, 512, 4302848, 8404};
  if (out_size != 4800576) {
    diag_k<<<1, 64, 0, stream>>>((float*)d_out, 9800000.f);
    return;
  }
  float* out_fsmn = (float*)d_out;
  float* out_keys = out_fsmn + (size_t)LAY * HID * (KW - 1 + TT);
  float* out_vals = out_keys + (size_t)LAY * NHD * DKH * LBN;
  float* out_ids  = out_vals + (size_t)LAY * NHD * LBN * DKH;
  if (n_in < 34) {
    diag_k<<<1, 64, 0, stream>>>(out_ids, 9900000.f);
    return;
  }
  for (int i = 0; i < 34; ++i) {
    if (EXPECT[i] >= 0 && in_sizes[i] != EXPECT[i]) {
      diag_k<<<1, 64, 0, stream>>>(out_ids, (float)((i + 1) * 100000));
      return;
    }
  }
  const long per = (long)LAY * NHD * DKH;
  const long ckl = (long)in_sizes[3] / per;
  if ((long)in_sizes[3] != ckl * per || in_sizes[4] != in_sizes[3] ||
      ckl <= 0 || (ckl & 63) != 0 || ckl > 6144) {
    diag_k<<<1, 64, 0, stream>>>(out_fsmn, (float)in_sizes[3]);
    return;
  }
  if (ws_size < (size_t)3145728 * 4) {
    diag_k<<<1, 64, 0, stream>>>(out_fsmn, 1.0e6f + (float)(ws_size >> 20));
    return;
  }
  const int ckv = (int)ckl;
  const int sct = ckv + SEQ;
  const int ncho = (ckv / 64 < 8) ? (ckv / 64) : 8;

  const float* enc    = (const float*)d_in[0];
  const float* lfrm   = (const float*)d_in[1];
  const float* fcache = (const float*)d_in[2];
  const float* kcache = (const float*)d_in[3];
  const float* vcache = (const float*)d_in[4];
  const float* n1g = (const float*)d_in[5];  const float* n1b = (const float*)d_in[6];
  const float* n2g = (const float*)d_in[7];  const float* n2b = (const float*)d_in[8];
  const float* n3g = (const float*)d_in[9];  const float* n3b = (const float*)d_in[10];
  const float* fng = (const float*)d_in[11]; const float* fnb = (const float*)d_in[12];
  const float* w1  = (const float*)d_in[13]; const float* b1  = (const float*)d_in[14];
  const float* w2  = (const float*)d_in[15];
  const float* fw  = (const float*)d_in[16];
  const float* qw  = (const float*)d_in[17]; const float* qbi  = (const float*)d_in[18];
  const float* kvw = (const float*)d_in[19]; const float* kvbi = (const float*)d_in[20];
  const float* ow  = (const float*)d_in[21]; const float* obi  = (const float*)d_in[22];
  const float* d3n1g = (const float*)d_in[23]; const float* d3n1b = (const float*)d_in[24];
  const float* d3w1  = (const float*)d_in[25]; const float* d3b1  = (const float*)d_in[26];
  const float* d3fng = (const float*)d_in[27]; const float* d3fnb = (const float*)d_in[28];
  const float* d3w2  = (const float*)d_in[29];
  const float* ang   = (const float*)d_in[30]; const float* anb = (const float*)d_in[31];
  const float* outw  = (const float*)d_in[32]; const float* outb = (const float*)d_in[33];

  // d_out scratch (proven layout); keys/vals regions overwritten by kvsave_k
  float* sc  = out_keys;
  float* ov  = out_vals;
  float* lf  = ov + 0;
  float* y1  = ov + 32768;
  float* y4  = ov + 98304;
  float* xb  = ov + 131072;
  float* ctx = ov + 196608;   // qp buffer (131072 floats available here)
  float* y2  = ov + 360448;   // also ctx-reduce output
  float* rs  = ov + 753920;
  float* lg  = ov + 754176;
  float* wsf   = (float*)d_ws;
  float* part  = wsf;
  float* partE = wsf + 1048576;
  float* partN = wsf + 2097152;

  const float alpha = 0.08838834764831845f;
  const long pz_ctx = (long)(ncho + 4) * 64 * DKH;

  CA ca;
  ca.enc = enc; ca.lfrm = lfrm; ca.fcache = fcache; ca.kcache = kcache; ca.vcache = vcache;
  ca.n1g = n1g; ca.n1b = n1b; ca.n2g = n2g; ca.n2b = n2b; ca.n3g = n3g; ca.n3b = n3b;
  ca.fng = fng; ca.fnb = fnb; ca.w1 = w1; ca.b1 = b1; ca.w2 = w2; ca.fw = fw;
  ca.qw = qw; ca.qbi = qbi; ca.kvw = kvw; ca.kvbi = kvbi; ca.ow = ow; ca.obi = obi;
  ca.d3n1g = d3n1g; ca.d3n1b = d3n1b; ca.d3w1 = d3w1; ca.d3b1 = d3b1;
  ca.d3fng = d3fng; ca.d3fnb = d3fnb; ca.d3w2 = d3w2;
  ca.ang = ang; ca.anb = anb; ca.outw = outw; ca.outb = outb;
  ca.lf = lf; ca.y1 = y1; ca.y2 = y2; ca.y4 = y4; ca.xb = xb; ca.ctx = ctx;
  ca.rs = rs; ca.lg = lg; ca.sc = sc;
  ca.part = part; ca.partE = partE; ca.partN = partN;
  ca.out_fsmn = out_fsmn; ca.out_ids = out_ids;
  ca.ckv = ckv; ca.sct = sct; ca.ncho = ncho; ca.pz_ctx = pz_ctx;

  // ---- occupancy-clamped cooperative launch (deadlock-proof) ----
  bool coopDone = false;
  int maxPerCU = 0;
  hipError_t qrc = hipOccupancyMaxActiveBlocksPerMultiprocessor(&maxPerCU, chain_k,
                                                                256, 0);
  if (qrc == hipSuccess && maxPerCU > 0) {
    int grid = maxPerCU * 256;        // 256 CUs on MI355X
    if (grid > 512) grid = 512;
    void* args[] = {(void*)&ca};
    hipError_t rc = hipLaunchCooperativeKernel((const void*)chain_k, dim3(grid),
                                               dim3(256), args, 0, stream);
    coopDone = (rc == hipSuccess);
  }

  if (!coopDone) {
    // -------- fallback: per-stage launch sequence (r16 math, proven) --------
    redln_k<<<TT, 256, 0, stream>>>(lfrm, HID, 1, nullptr, nullptr, 0, n1g, n1b, lf, y1);
    for (int l = 0; l < LAY; ++l) {
      const float* Wkv = kvw + (size_t)l * HID * 2 * HID;
      const float* Bkv = kvbi + (size_t)l * 2 * HID;
      const float* qbi_l = qbi + (size_t)l * HID;
      gemm32_k<<<512, 256, 0, stream>>>(y1, HID, 0, w1 + (size_t)l * HID * FF, FF, 0,
                                        FF, HID, 8, 1, part, 0, 0, 1, 0);
      redln_k<<<TT, 256, 0, stream>>>(part, FF, 8, b1 + (size_t)l * FF, nullptr, 1,
                                      fng + (size_t)l * FF, fnb + (size_t)l * FF, nullptr, y2);
      gemm32_k<<<512, 256, 0, stream>>>(y2, FF, 0, w2 + (size_t)l * FF * HID, HID, 0,
                                        HID, FF, 32, 1, part, 0, 0, 1, 0);
      redln_k<<<TT, 256, 0, stream>>>(part, HID, 32, nullptr, nullptr, 0,
                                      n2g + l * HID, n2b + l * HID, nullptr, y4);
      fsmnln_k<<<TT, 256, 0, stream>>>(y4, lf, fcache + (size_t)l * HID * (KW - 1),
                                       fw + (size_t)l * HID * KW, n3g + l * HID, n3b + l * HID,
                                       xb, out_fsmn + (size_t)l * HID * (KW - 1 + TT), y1);
      gemm32_k<<<128, 256, 0, stream>>>(y1, HID, 0, qw + (size_t)l * HID * HID, HID, 0,
                                        HID, HID, 8, 1, part, 0, 0, 1, 0);
      attn1_k<<<(8 + ckv / 64) * NHD, 256, 0, stream>>>(
          part, qbi_l, Wkv, kcache + (size_t)l * NHD * DKH * ckv, ctx, sc, ckv, sct);
      scnew_k<<<256, 256, 0, stream>>>(ctx, enc, sc, partN, ckv, sct);
      softmax_k<<<NHD * TT, 256, 0, stream>>>(sc, rs, part, qbi_l, Bkv, partN, sct, ckv, alpha);
      attn2_k<<<320, 256, 0, stream>>>(sc, vcache + (size_t)l * NHD * ckv * DKH, enc,
                                       part, partE, ckv, sct, ncho, pz_ctx);
      gemm32_k<<<64, 256, 0, stream>>>(partE, HID, 8L * 64 * HID, Wkv + HID, 2 * HID, DKH,
                                       DKH, HID, 4, NHD, part, pz_ctx, ncho, 8, 64L * HID);
      red_k<<<128, 256, 0, stream>>>(part, y2, DKH, ncho + 4, pz_ctx, HID, DKH,
                                     rs, Bkv + HID, NHD * TT * DKH);
      gemm32_k<<<128, 256, 0, stream>>>(y2, HID, 0, ow + (size_t)l * HID * HID, HID, 0,
                                        HID, HID, 8, 1, part, 0, 0, 1, 0);
      const float* ng = (l + 1 < LAY) ? n1g + (l + 1) * HID : d3n1g;
      const float* nb = (l + 1 < LAY) ? n1b + (l + 1) * HID : d3n1b;
      redln_k<<<TT, 256, 0, stream>>>(part, HID, 8, obi + (size_t)l * HID, xb, 0, ng, nb, lf, y1);
    }
    gemm32_k<<<512, 256, 0, stream>>>(y1, HID, 0, d3w1, FF, 0, FF, HID, 8, 1, part, 0, 0, 1, 0);
    redln_k<<<TT, 256, 0, stream>>>(part, FF, 8, d3b1, nullptr, 1, d3fng, d3fnb, nullptr, y2);
    gemm32_k<<<512, 256, 0, stream>>>(y2, FF, 0, d3w2, HID, 0, HID, FF, 32, 1, part, 0, 0, 1, 0);
    redln_k<<<TT, 256, 0, stream>>>(part, HID, 32, nullptr, nullptr, 0, ang, anb, nullptr, y4);
    vocab_k<<<132, 256, 0, stream>>>(y4, outw, lg, outb);
    argmax_k<<<TT, 256, 0, stream>>>(lg, out_ids);
  }

  // ---- LAST: overwrite scratch regions with real save_keys / save_values ---
  kvsave_k<<<dim3(2 * HID / 64, LBN / 64, LAY), 256, 0, stream>>>(
      enc, kvw, kvbi, out_keys, out_vals);
}

// Round 19
// 2927.691 us; speedup vs baseline: 1.0920x; 1.0920x over previous
//
#include <hip/hip_runtime.h>

// Paraformer-large streaming decoder dims (CKV derived at runtime from in_sizes)
constexpr int LAY = 16, HID = 512, FF = 2048, NHD = 4, DKH = 128, KW = 11,
              VOC = 8404, TT = 64, SEQ = 2048, LBN = 256;

// LDS XOR swizzle (proven r13): kills 8-way store conflicts
#define SWZ(row, e) ((e) ^ ((((row) >> 2) & 7) << 2))

// ---------------- diagnostic: write value to 64 floats ----------------
__global__ void diag_k(float* __restrict__ p, float v) { p[threadIdx.x] = v; }

// ---- fused split-K reduce + bias/res/relu + LayerNorm (one block per row) --
__global__ __launch_bounds__(256) void redln_k(
    const float* __restrict__ P, int N, int nch,
    const float* __restrict__ bias, const float* __restrict__ res, int relu,
    const float* __restrict__ g, const float* __restrict__ b,
    float* __restrict__ out1, float* __restrict__ out2) {
  __shared__ float buf[2048];
  __shared__ float red[256];
  const int m = blockIdx.x, tid = threadIdx.x;
  float s = 0.f;
  for (int n = tid; n < N; n += 256) {
    const float* p = P + (size_t)m * N + n;
    float v = 0.f;
    for (int c = 0; c < nch; ++c) v += p[(size_t)c * 64 * N];
    if (bias) v += bias[n];
    if (res) v += res[(size_t)m * N + n];
    if (relu) v = fmaxf(v, 0.f);
    if (out1) out1[(size_t)m * N + n] = v;
    buf[n] = v; s += v;
  }
  red[tid] = s; __syncthreads();
  for (int st = 128; st > 0; st >>= 1) { if (tid < st) red[tid] += red[tid + st]; __syncthreads(); }
  const float mean = red[0] / N;
  __syncthreads();
  float vs = 0.f;
  for (int n = tid; n < N; n += 256) { float d = buf[n] - mean; vs += d * d; }
  red[tid] = vs; __syncthreads();
  for (int st = 128; st > 0; st >>= 1) { if (tid < st) red[tid] += red[tid + st]; __syncthreads(); }
  const float inv = rsqrtf(red[0] / N + 1e-5f);
  for (int n = tid; n < N; n += 256)
    out2[(size_t)m * N + n] = (buf[n] - mean) * inv * g[n] + b[n];
}

// ---- gemm32_nn: 64x32-tile split-K partial GEMM ----------------------------
// grid (N/32, nch, Z). Writes partials part[z*pzs + (coff+chunk)*64*N + ...].
// Normal A mode: aCh chunks (stride aChS) summed on load.
// ctx mode (rsA != null): A element (r,k) = sum_{c<aCh} A[(k>>7)*pzA + c*8192
//   + r*128 + (k&127)] + rsA[(k>>7)*64 + r] * bvA[k]  (folds old red_k stage).
__global__ __launch_bounds__(256) void gemm32_nn(
    const float* __restrict__ A, int lda, long sA,
    const float* __restrict__ B, int ldb, long sB,
    int N, int Kd, int nch,
    float* __restrict__ part, long pzs, int coff,
    int aCh, long aChS,
    const float* __restrict__ rsA, const float* __restrict__ bvA, long pzA) {
  __shared__ float As[64][64];
  __shared__ float Bs[64][40];
  const int tid = threadIdx.x;
  const int l16r = tid >> 4, l16c = tid & 15;  // A-load decomposition
  const int lr = tid >> 3, lc = tid & 7;       // compute decomposition
  const int bn = blockIdx.x * 32;
  const int chunk = blockIdx.y;
  const int z = blockIdx.z;
  A += (long)z * sA; B += (long)z * sB;
  float acc[2][4] = {};
  const int ktiles = Kd >> 6;
  const int fa = (l16c & 7) << 2;
  for (int kt = chunk; kt < ktiles; kt += nch) {
    const int k0 = kt << 6;
    __syncthreads();
#pragma unroll
    for (int i = 0; i < 4; ++i) {
      const int r = l16r + 16 * i;
      float4 av;
      if (rsA) {
        const int kcol = k0 + l16c * 4;
        const int zz = kcol >> 7, d = kcol & 127;
        const float* ap = A + (size_t)zz * pzA + (size_t)r * 128 + d;
        av = *(const float4*)ap;
        for (int c = 1; c < aCh; ++c) {
          const float4 t2 = *(const float4*)(ap + (size_t)c * aChS);
          av.x += t2.x; av.y += t2.y; av.z += t2.z; av.w += t2.w;
        }
        const float4 bb = *(const float4*)(bvA + kcol);
        const float rv = rsA[zz * 64 + r];
        av.x += rv * bb.x; av.y += rv * bb.y; av.z += rv * bb.z; av.w += rv * bb.w;
      } else {
        const float* ap = A + (size_t)r * lda + k0 + l16c * 4;
        av = *(const float4*)ap;
        for (int c = 1; c < aCh; ++c) {
          const float4 t2 = *(const float4*)(ap + (size_t)c * aChS);
          av.x += t2.x; av.y += t2.y; av.z += t2.z; av.w += t2.w;
        }
      }
      As[l16c * 4 + 0][r ^ fa] = av.x; As[l16c * 4 + 1][r ^ fa] = av.y;
      As[l16c * 4 + 2][r ^ fa] = av.z; As[l16c * 4 + 3][r ^ fa] = av.w;
    }
#pragma unroll
    for (int i = 0; i < 2; ++i) {
      const int rb = lr + 32 * i;
      const float4 bv = *(const float4*)(B + (size_t)(k0 + rb) * ldb + bn + lc * 4);
      *(float4*)(&Bs[rb][lc * 4]) = bv;
    }
    __syncthreads();
#pragma unroll 8
    for (int kk = 0; kk < 64; ++kk) {
      const int fk = ((kk >> 2) & 7) << 2;
      const float2 a = *(const float2*)(&As[kk][(lr * 2) ^ fk]);
      const float4 b = *(const float4*)(&Bs[kk][lc * 4]);
      acc[0][0] += a.x * b.x; acc[0][1] += a.x * b.y; acc[0][2] += a.x * b.z; acc[0][3] += a.x * b.w;
      acc[1][0] += a.y * b.x; acc[1][1] += a.y * b.y; acc[1][2] += a.y * b.z; acc[1][3] += a.y * b.w;
    }
  }
  float* P = part + (size_t)z * pzs + (size_t)(coff + chunk) * 64 * N;
#pragma unroll
  for (int i = 0; i < 2; ++i) {
    const int m = lr * 2 + i;
#pragma unroll
    for (int j = 0; j < 4; ++j) P[(size_t)m * N + bn + lc * 4 + j] = acc[i][j];
  }
}

// ---------------- gemm_nn: C[64,N] = A[64,K] @ B[K,N] (vocab etc.) ----------
__global__ __launch_bounds__(256) void gemm_nn(
    const float* __restrict__ A, int lda, long sA,
    const float* __restrict__ B, int ldb, long sB,
    float* __restrict__ C, int ldc, long sC,
    const float* __restrict__ bias,
    const float* __restrict__ res, int ldres,
    int N, int Kd, int flags, int nch,
    float* __restrict__ part, long pzs, int coff,
    int aCh, long aChS) {
  __shared__ float As[64][64];
  __shared__ float Bs[64][64];
  const int tid = threadIdx.x;
  const int lr = tid >> 4, lc = tid & 15;
  const int bn = blockIdx.x * 64;
  const int chunk = blockIdx.y;
  const int z = blockIdx.z;
  A += (long)z * sA; B += (long)z * sB; C += (long)z * sC;
  float acc[4][4] = {};
  const int ktiles = Kd >> 6;
  const int fa = (lc & 7) << 2;
  for (int kt = chunk; kt < ktiles; kt += nch) {
    const int k0 = kt << 6;
    __syncthreads();
#pragma unroll
    for (int i = 0; i < 4; ++i) {
      const int r = lr + 16 * i;
      const float* ap = A + (size_t)r * lda + k0 + lc * 4;
      float4 av = *(const float4*)ap;
      for (int c = 1; c < aCh; ++c) {
        const float4 t2 = *(const float4*)(ap + (size_t)c * aChS);
        av.x += t2.x; av.y += t2.y; av.z += t2.z; av.w += t2.w;
      }
      As[lc * 4 + 0][r ^ fa] = av.x; As[lc * 4 + 1][r ^ fa] = av.y;
      As[lc * 4 + 2][r ^ fa] = av.z; As[lc * 4 + 3][r ^ fa] = av.w;
      const int n = bn + lc * 4;
      const float* bp = B + (size_t)(k0 + r) * ldb + n;
      float4 bv;
      if (n + 3 < N) bv = *(const float4*)bp;
      else {
        bv.x = (n + 0 < N) ? bp[0] : 0.f;
        bv.y = (n + 1 < N) ? bp[1] : 0.f;
        bv.z = (n + 2 < N) ? bp[2] : 0.f;
        bv.w = (n + 3 < N) ? bp[3] : 0.f;
      }
      *(float4*)(&Bs[r][SWZ(r, lc * 4)]) = bv;
    }
    __syncthreads();
#pragma unroll 8
    for (int kk = 0; kk < 64; ++kk) {
      const int fk = ((kk >> 2) & 7) << 2;
      const float4 a = *(const float4*)(&As[kk][(lr * 4) ^ fk]);
      const float4 b = *(const float4*)(&Bs[kk][(lc * 4) ^ fk]);
      acc[0][0] += a.x * b.x; acc[0][1] += a.x * b.y; acc[0][2] += a.x * b.z; acc[0][3] += a.x * b.w;
      acc[1][0] += a.y * b.x; acc[1][1] += a.y * b.y; acc[1][2] += a.y * b.z; acc[1][3] += a.y * b.w;
      acc[2][0] += a.z * b.x; acc[2][1] += a.z * b.y; acc[2][2] += a.z * b.z; acc[2][3] += a.z * b.w;
      acc[3][0] += a.w * b.x; acc[3][1] += a.w * b.y; acc[3][2] += a.w * b.z; acc[3][3] += a.w * b.w;
    }
  }
  if (part) {
    float* P = part + (size_t)z * pzs + (size_t)(coff + chunk) * 64 * N;
#pragma unroll
    for (int i = 0; i < 4; ++i) {
      const int m = lr * 4 + i;
#pragma unroll
      for (int j = 0; j < 4; ++j) P[(size_t)m * N + bn + lc * 4 + j] = acc[i][j];
    }
    return;
  }
#pragma unroll
  for (int i = 0; i < 4; ++i) {
    const int m = lr * 4 + i;
#pragma unroll
    for (int j = 0; j < 4; ++j) {
      const int n = bn + lc * 4 + j;
      if (n < N) {
        float v = acc[i][j];
        if (bias) v += bias[n];
        if (res) v += res[(size_t)m * ldres + n];
        if (flags & 2) v += C[(size_t)m * ldc + n];
        if (flags & 1) v = fmaxf(v, 0.f);
        C[(size_t)m * ldc + n] = v;
      }
    }
  }
}

// ---- gemm_nt: C[64,N] = A[64,K] @ B^T, splitK nch (chunk0->C, c>=1->part) --
__global__ __launch_bounds__(256) void gemm_nt(
    const float* __restrict__ A, int lda, long sA,
    const float* __restrict__ B, int ldb, long sB,
    float* __restrict__ C, int ldc, long sC,
    int N, int Kd, int nch, float* __restrict__ part) {
  __shared__ float As[64][64];
  __shared__ float Bs[64][64];
  const int tid = threadIdx.x;
  const int lr = tid >> 4, lc = tid & 15;
  const int bn = blockIdx.x * 64;
  const int chunk = blockIdx.y;
  const int z = blockIdx.z;
  A += (long)z * sA; B += (long)z * sB; C += (long)z * sC;
  float acc[4][4] = {};
  const int ktiles = Kd >> 6;
  const int fa = (lc & 7) << 2;
  for (int kt = chunk; kt < ktiles; kt += nch) {
    const int k0 = kt << 6;
    __syncthreads();
#pragma unroll
    for (int i = 0; i < 4; ++i) {
      const int r = lr + 16 * i;
      const float4 av = *(const float4*)(A + (size_t)r * lda + k0 + lc * 4);
      As[lc * 4 + 0][r ^ fa] = av.x; As[lc * 4 + 1][r ^ fa] = av.y;
      As[lc * 4 + 2][r ^ fa] = av.z; As[lc * 4 + 3][r ^ fa] = av.w;
      const float4 bv = *(const float4*)(B + (size_t)(bn + r) * ldb + k0 + lc * 4);
      Bs[lc * 4 + 0][r ^ fa] = bv.x; Bs[lc * 4 + 1][r ^ fa] = bv.y;
      Bs[lc * 4 + 2][r ^ fa] = bv.z; Bs[lc * 4 + 3][r ^ fa] = bv.w;
    }
    __syncthreads();
#pragma unroll 8
    for (int kk = 0; kk < 64; ++kk) {
      const int fk = ((kk >> 2) & 7) << 2;
      const float4 a = *(const float4*)(&As[kk][(lr * 4) ^ fk]);
      const float4 b = *(const float4*)(&Bs[kk][(lc * 4) ^ fk]);
      acc[0][0] += a.x * b.x; acc[0][1] += a.x * b.y; acc[0][2] += a.x * b.z; acc[0][3] += a.x * b.w;
      acc[1][0] += a.y * b.x; acc[1][1] += a.y * b.y; acc[1][2] += a.y * b.z; acc[1][3] += a.y * b.w;
      acc[2][0] += a.z * b.x; acc[2][1] += a.z * b.y; acc[2][2] += a.z * b.z; acc[2][3] += a.z * b.w;
      acc[3][0] += a.w * b.x; acc[3][1] += a.w * b.y; acc[3][2] += a.w * b.z; acc[3][3] += a.w * b.w;
    }
  }
  if (chunk == 0) {
#pragma unroll
    for (int i = 0; i < 4; ++i)
#pragma unroll
      for (int j = 0; j < 4; ++j)
        C[(size_t)(lr * 4 + i) * ldc + bn + lc * 4 + j] = acc[i][j];
  } else {
    float* P = part + (size_t)z * (64L * SEQ) + (size_t)(chunk - 1) * 64 * SEQ * NHD;
#pragma unroll
    for (int i = 0; i < 4; ++i)
#pragma unroll
      for (int j = 0; j < 4; ++j)
        P[(size_t)(lr * 4 + i) * SEQ + bn + lc * 4 + j] = acc[i][j];
  }
}

// ---- merged: qp (NT vs Wk) + scores-old (NN vs kcache) ---------------------
__global__ __launch_bounds__(256) void attn1_k(
    const float* __restrict__ qpart, const float* __restrict__ qbi_l,
    const float* __restrict__ Wkv, const float* __restrict__ kcl,
    float* __restrict__ qp, float* __restrict__ sc,
    int ckv, int sct) {
  __shared__ float As[64][64];
  __shared__ float Bs[64][64];
  const int tid = threadIdx.x;
  const int lr = tid >> 4, lc = tid & 15;
  const int h = blockIdx.z;
  const bool isQp = blockIdx.x < 8;
  const int bn = (isQp ? blockIdx.x : blockIdx.x - 8) * 64;
  const int fa = (lc & 7) << 2;
  float acc[4][4] = {};
  for (int k0 = 0; k0 < DKH; k0 += 64) {
    __syncthreads();
#pragma unroll
    for (int i = 0; i < 4; ++i) {
      const int r = lr + 16 * i;
      const float* ap = qpart + (size_t)r * HID + h * DKH + k0 + lc * 4;
      float4 av = *(const float4*)ap;
      for (int c = 1; c < 8; ++c) {
        const float4 t2 = *(const float4*)(ap + (size_t)c * 64 * HID);
        av.x += t2.x; av.y += t2.y; av.z += t2.z; av.w += t2.w;
      }
      const float4 bb = *(const float4*)(qbi_l + h * DKH + k0 + lc * 4);
      av.x += bb.x; av.y += bb.y; av.z += bb.z; av.w += bb.w;
      As[lc * 4 + 0][r ^ fa] = av.x; As[lc * 4 + 1][r ^ fa] = av.y;
      As[lc * 4 + 2][r ^ fa] = av.z; As[lc * 4 + 3][r ^ fa] = av.w;
      if (isQp) {
        const float4 bv = *(const float4*)(Wkv + (size_t)(bn + r) * (2 * HID) + h * DKH + k0 + lc * 4);
        Bs[lc * 4 + 0][r ^ fa] = bv.x; Bs[lc * 4 + 1][r ^ fa] = bv.y;
        Bs[lc * 4 + 2][r ^ fa] = bv.z; Bs[lc * 4 + 3][r ^ fa] = bv.w;
      } else {
        const float4 bv = *(const float4*)(kcl + ((size_t)h * DKH + k0 + r) * ckv + bn + lc * 4);
        *(float4*)(&Bs[r][SWZ(r, lc * 4)]) = bv;
      }
    }
    __syncthreads();
#pragma unroll 8
    for (int kk = 0; kk < 64; ++kk) {
      const int fk = ((kk >> 2) & 7) << 2;
      const float4 a = *(const float4*)(&As[kk][(lr * 4) ^ fk]);
      const float4 b = *(const float4*)(&Bs[kk][(lc * 4) ^ fk]);
      acc[0][0] += a.x * b.x; acc[0][1] += a.x * b.y; acc[0][2] += a.x * b.z; acc[0][3] += a.x * b.w;
      acc[1][0] += a.y * b.x; acc[1][1] += a.y * b.y; acc[1][2] += a.y * b.z; acc[1][3] += a.y * b.w;
      acc[2][0] += a.z * b.x; acc[2][1] += a.z * b.y; acc[2][2] += a.z * b.z; acc[2][3] += a.z * b.w;
      acc[3][0] += a.w * b.x; acc[3][1] += a.w * b.y; acc[3][2] += a.w * b.z; acc[3][3] += a.w * b.w;
    }
  }
  if (isQp) {
    float* C = qp + (size_t)h * TT * HID;
#pragma unroll
    for (int i = 0; i < 4; ++i)
#pragma unroll
      for (int j = 0; j < 4; ++j)
        C[(size_t)(lr * 4 + i) * HID + bn + lc * 4 + j] = acc[i][j];
  } else {
    float* C = sc + (size_t)h * TT * sct;
#pragma unroll
    for (int i = 0; i < 4; ++i)
#pragma unroll
      for (int j = 0; j < 4; ++j)
        C[(size_t)(lr * 4 + i) * sct + bn + lc * 4 + j] = acc[i][j];
  }
}

// ---- merged ctx partials: ctx-old (split ncho) + ctxE (split 8) ------------
__global__ __launch_bounds__(256) void attn2_k(
    const float* __restrict__ sc, const float* __restrict__ vcl,
    const float* __restrict__ enc,
    float* __restrict__ part, float* __restrict__ partE,
    int ckv, int sct, int ncho, long pzc) {
  __shared__ float As[64][64];
  __shared__ float Bs[64][64];
  const int tid = threadIdx.x;
  const int lr = tid >> 4, lc = tid & 15;
  const int h = blockIdx.z;
  const int by = blockIdx.y;
  const bool isOld = blockIdx.x < 2;
  if (isOld && by >= ncho) return;
  if (!isOld && by >= 8) return;
  const float* A;
  const float* Bb;
  int lda, ldb, N, ktiles, nch, bn;
  float* P;
  if (isOld) {
    A = sc + (size_t)h * TT * sct;  lda = sct;
    Bb = vcl + (size_t)h * ckv * DKH; ldb = DKH;
    N = DKH; ktiles = ckv >> 6; nch = ncho; bn = blockIdx.x * 64;
    P = part + (size_t)h * pzc + (size_t)by * 64 * DKH;
  } else {
    A = sc + ckv + (size_t)h * TT * sct; lda = sct;
    Bb = enc; ldb = HID;
    N = HID; ktiles = SEQ >> 6; nch = 8; bn = (blockIdx.x - 2) * 64;
    P = partE + (size_t)h * (8L * 64 * HID) + (size_t)by * 64 * HID;
  }
  const int fa = (lc & 7) << 2;
  float acc[4][4] = {};
  for (int kt = by; kt < ktiles; kt += nch) {
    const int k0 = kt << 6;
    __syncthreads();
#pragma unroll
    for (int i = 0; i < 4; ++i) {
      const int r = lr + 16 * i;
      const float4 av = *(const float4*)(A + (size_t)r * lda + k0 + lc * 4);
      As[lc * 4 + 0][r ^ fa] = av.x; As[lc * 4 + 1][r ^ fa] = av.y;
      As[lc * 4 + 2][r ^ fa] = av.z; As[lc * 4 + 3][r ^ fa] = av.w;
      const float4 bv = *(const float4*)(Bb + (size_t)(k0 + r) * ldb + bn + lc * 4);
      *(float4*)(&Bs[r][SWZ(r, lc * 4)]) = bv;
    }
    __syncthreads();
#pragma unroll 8
    for (int kk = 0; kk < 64; ++kk) {
      const int fk = ((kk >> 2) & 7) << 2;
      const float4 a = *(const float4*)(&As[kk][(lr * 4) ^ fk]);
      const float4 b = *(const float4*)(&Bs[kk][(lc * 4) ^ fk]);
      acc[0][0] += a.x * b.x; acc[0][1] += a.x * b.y; acc[0][2] += a.x * b.z; acc[0][3] += a.x * b.w;
      acc[1][0] += a.y * b.x; acc[1][1] += a.y * b.y; acc[1][2] += a.y * b.z; acc[1][3] += a.y * b.w;
      acc[2][0] += a.z * b.x; acc[2][1] += a.z * b.y; acc[2][2] += a.z * b.z; acc[2][3] += a.z * b.w;
      acc[3][0] += a.w * b.x; acc[3][1] += a.w * b.y; acc[3][2] += a.w * b.z; acc[3][3] += a.w * b.w;
    }
  }
#pragma unroll
  for (int i = 0; i < 4; ++i)
#pragma unroll
    for (int j = 0; j < 4; ++j)
      P[(size_t)(lr * 4 + i) * N + bn + lc * 4 + j] = acc[i][j];
}

// ---- fused FSMN conv + residuals + x_cat + LN3 (one block per row t) -------
__global__ __launch_bounds__(256) void fsmnln_k(
    const float* __restrict__ y4, const float* __restrict__ lfin,
    const float* __restrict__ cache, const float* __restrict__ fw,
    const float* __restrict__ g, const float* __restrict__ b,
    float* __restrict__ xb, float* __restrict__ xcat,
    float* __restrict__ y1out) {
  __shared__ float buf[HID];
  __shared__ float red[256];
  const int t = blockIdx.x, tid = threadIdx.x;
  float s = 0.f;
  for (int h = tid; h < HID; h += 256) {
    float conv = 0.f;
#pragma unroll
    for (int k = 0; k < KW; ++k) {
      const int j = t + k;
      const float xcv = (j < KW - 1) ? cache[h * (KW - 1) + j]
                                     : y4[(size_t)(j - (KW - 1)) * HID + h];
      conv += xcv * fw[h * KW + k];
    }
    const float yv = y4[(size_t)t * HID + h];
    const float x = conv + yv + lfin[(size_t)t * HID + h];
    xb[(size_t)t * HID + h] = x;
    buf[h] = x; s += x;
    xcat[h * (KW - 1 + TT) + (KW - 1) + t] = yv;
    if (t == 0) {
      for (int j2 = 0; j2 < KW - 1; ++j2)
        xcat[h * (KW - 1 + TT) + j2] = cache[h * (KW - 1) + j2];
    }
  }
  red[tid] = s; __syncthreads();
  for (int st = 128; st > 0; st >>= 1) { if (tid < st) red[tid] += red[tid + st]; __syncthreads(); }
  const float mean = red[0] / HID;
  __syncthreads();
  float vs = 0.f;
  for (int h = tid; h < HID; h += 256) { float d = buf[h] - mean; vs += d * d; }
  red[tid] = vs; __syncthreads();
  for (int st = 128; st > 0; st >>= 1) { if (tid < st) red[tid] += red[tid + st]; __syncthreads(); }
  const float inv = rsqrtf(red[0] / HID + 1e-5f);
  for (int h = tid; h < HID; h += 256)
    y1out[(size_t)t * HID + h] = (buf[h] - mean) * inv * g[h] + b[h];
}

// ---- single-pass LDS row softmax; fused qc-dot + scores-new partial sum ----
__global__ __launch_bounds__(256) void softmax_k(
    float* __restrict__ sc, float* __restrict__ rs,
    const float* __restrict__ qpart, const float* __restrict__ qbi_l,
    const float* __restrict__ kb, const float* __restrict__ partN,
    int cols, int newStart, float alpha) {
  __shared__ float srow[8192];
  __shared__ float red[256];
  const int tid = threadIdx.x;
  const int row = blockIdx.x;
  const int h = row >> 6, t = row & 63;
  sc += (size_t)row * cols;
  const float* pn = partN + (size_t)h * 64 * SEQ + (size_t)t * SEQ;
  float qv = 0.f;
  if (tid < DKH) {
    const float* qp0 = qpart + (size_t)t * HID + h * DKH + tid;
    float q = qp0[0];
    for (int c = 1; c < 8; ++c) q += qp0[(size_t)c * 64 * HID];
    q += qbi_l[h * DKH + tid];
    qv = q * kb[h * DKH + tid];
  }
  red[tid] = qv; __syncthreads();
  for (int st = 64; st > 0; st >>= 1) { if (tid < st) red[tid] += red[tid + st]; __syncthreads(); }
  const float qcv = red[0];
  __syncthreads();
  float m = -3.4e38f;
  for (int c = tid; c < cols; c += 256) {
    float v = sc[c];
    if (c >= newStart) v += pn[c - newStart] + qcv;
    v *= alpha;
    srow[c] = v; m = fmaxf(m, v);
  }
  red[tid] = m; __syncthreads();
  for (int st = 128; st > 0; st >>= 1) { if (tid < st) red[tid] = fmaxf(red[tid], red[tid + st]); __syncthreads(); }
  m = red[0]; __syncthreads();
  float s = 0.f;
  for (int c = tid; c < cols; c += 256) {
    const float e = __expf(srow[c] - m);
    srow[c] = e; s += e;
  }
  red[tid] = s; __syncthreads();
  for (int st = 128; st > 0; st >>= 1) { if (tid < st) red[tid] += red[tid + st]; __syncthreads(); }
  const float inv = 1.f / red[0];
  float ns = 0.f;
  for (int c = tid; c < cols; c += 256) {
    const float p = srow[c] * inv; sc[c] = p;
    if (c >= newStart) ns += p;
  }
  __syncthreads();
  red[tid] = ns; __syncthreads();
  for (int st = 128; st > 0; st >>= 1) { if (tid < st) red[tid] += red[tid + st]; __syncthreads(); }
  if (tid == 0) rs[row] = red[0];
}

// ---------------- Argmax over vocab (first-max tie-break), float out --------
__global__ __launch_bounds__(256) void argmax_k(const float* __restrict__ lg,
                                                float* __restrict__ out) {
  __shared__ float vs[256];
  __shared__ int ix[256];
  const int tid = threadIdx.x;
  lg += (size_t)blockIdx.x * VOC;
  float bm = -3.4e38f;
  int bi = 0;
  for (int c = tid; c < VOC; c += 256) { float v = lg[c]; if (v > bm) { bm = v; bi = c; } }
  vs[tid] = bm; ix[tid] = bi; __syncthreads();
  for (int st = 128; st > 0; st >>= 1) {
    if (tid < st) {
      if (vs[tid + st] > vs[tid] || (vs[tid + st] == vs[tid] && ix[tid + st] < ix[tid])) {
        vs[tid] = vs[tid + st]; ix[tid] = ix[tid + st];
      }
    }
    __syncthreads();
  }
  if (tid == 0) out[blockIdx.x] = (float)ix[0];
}

// ---------------- save_keys / save_values (runs LAST; overwrites scratch) ---
__global__ __launch_bounds__(256) void kvsave_k(const float* __restrict__ enc,
                                                const float* __restrict__ kvw,
                                                const float* __restrict__ kvb,
                                                float* __restrict__ keys,
                                                float* __restrict__ vals) {
  __shared__ float As[64][64];
  __shared__ float Bs[64][64];
  const int tid = threadIdx.x;
  const int lr = tid >> 4, lc = tid & 15;
  const int bn = blockIdx.x * 64, bm = blockIdx.y * 64;
  const int l = blockIdx.z;
  const float* W = kvw + (size_t)l * HID * 2 * HID;
  const int fa = (lc & 7) << 2;
  float acc[4][4] = {};
  for (int k0 = 0; k0 < HID; k0 += 64) {
    __syncthreads();
#pragma unroll
    for (int i = 0; i < 4; ++i) {
      const int r = lr + 16 * i;
      const float4 av =
          *(const float4*)(enc + (size_t)(SEQ - LBN + bm + r) * HID + k0 + lc * 4);
      As[lc * 4 + 0][r ^ fa] = av.x; As[lc * 4 + 1][r ^ fa] = av.y;
      As[lc * 4 + 2][r ^ fa] = av.z; As[lc * 4 + 3][r ^ fa] = av.w;
      const float4 bv = *(const float4*)(W + (size_t)(k0 + r) * (2 * HID) + bn + lc * 4);
      *(float4*)(&Bs[r][SWZ(r, lc * 4)]) = bv;
    }
    __syncthreads();
#pragma unroll 8
    for (int kk = 0; kk < 64; ++kk) {
      const int fk = ((kk >> 2) & 7) << 2;
      const float4 a = *(const float4*)(&As[kk][(lr * 4) ^ fk]);
      const float4 b = *(const float4*)(&Bs[kk][(lc * 4) ^ fk]);
      acc[0][0] += a.x * b.x; acc[0][1] += a.x * b.y; acc[0][2] += a.x * b.z; acc[0][3] += a.x * b.w;
      acc[1][0] += a.y * b.x; acc[1][1] += a.y * b.y; acc[1][2] += a.y * b.z; acc[1][3] += a.y * b.w;
      acc[2][0] += a.z * b.x; acc[2][1] += a.z * b.y; acc[2][2] += a.z * b.z; acc[2][3] += a.z * b.w;
      acc[3][0] += a.w * b.x; acc[3][1] += a.w * b.y; acc[3][2] += a.w * b.z; acc[3][3] += a.w * b.w;
    }
  }
#pragma unroll
  for (int i = 0; i < 4; ++i) {
    const int m = bm + lr * 4 + i;
#pragma unroll
    for (int j = 0; j < 4; ++j) {
      const int n = bn + lc * 4 + j;
      const float v = acc[i][j] + kvb[(size_t)l * 2 * HID + n];
      if (n < 512) {
        const int h = n >> 7, d = n & 127;
        keys[(((size_t)l * NHD + h) * DKH + d) * LBN + m] = v;
      } else {
        const int c = n - 512, h = c >> 7, d = c & 127;
        vals[(((size_t)l * NHD + h) * LBN + m) * DKH + d] = v;
      }
    }
  }
}

extern "C" void kernel_launch(void* const* d_in, const int* in_sizes, int n_in,
                              void* d_out, int out_size, void* d_ws, size_t ws_size,
                              hipStream_t stream) {
  static const int EXPECT[34] = {
      1048576, 32768, 81920, -1, -1,
      8192, 8192, 8192, 8192, 8192, 8192,
      32768, 32768,
      16777216, 32768, 16777216, 90112,
      4194304, 8192, 8388608, 16384, 4194304, 8192,
      512, 512, 1048576, 2048, 2048, 2048, 1048576,
      512, 512, 4302848, 8404};
  if (out_size != 4800576) {
    diag_k<<<1, 64, 0, stream>>>((float*)d_out, 9800000.f);
    return;
  }
  float* out_fsmn = (float*)d_out;
  float* out_keys = out_fsmn + (size_t)LAY * HID * (KW - 1 + TT);
  float* out_vals = out_keys + (size_t)LAY * NHD * DKH * LBN;
  float* out_ids  = out_vals + (size_t)LAY * NHD * LBN * DKH;
  if (n_in < 34) {
    diag_k<<<1, 64, 0, stream>>>(out_ids, 9900000.f);
    return;
  }
  for (int i = 0; i < 34; ++i) {
    if (EXPECT[i] >= 0 && in_sizes[i] != EXPECT[i]) {
      diag_k<<<1, 64, 0, stream>>>(out_ids, (float)((i + 1) * 100000));
      return;
    }
  }
  const long per = (long)LAY * NHD * DKH;
  const long ckl = (long)in_sizes[3] / per;
  if ((long)in_sizes[3] != ckl * per || in_sizes[4] != in_sizes[3] ||
      ckl <= 0 || (ckl & 63) != 0 || ckl > 6144) {
    diag_k<<<1, 64, 0, stream>>>(out_fsmn, (float)in_sizes[3]);
    return;
  }
  if (ws_size < (size_t)3145728 * 4) {
    diag_k<<<1, 64, 0, stream>>>(out_fsmn, 1.0e6f + (float)(ws_size >> 20));
    return;
  }
  const int ckv = (int)ckl;
  const int sct = ckv + SEQ;
  const long TS = (long)TT * sct;
  const int ncho = (ckv / 64 < 8) ? (ckv / 64) : 8;

  const float* enc    = (const float*)d_in[0];
  const float* lfrm   = (const float*)d_in[1];
  const float* fcache = (const float*)d_in[2];
  const float* kcache = (const float*)d_in[3];
  const float* vcache = (const float*)d_in[4];
  const float* n1g = (const float*)d_in[5];  const float* n1b = (const float*)d_in[6];
  const float* n2g = (const float*)d_in[7];  const float* n2b = (const float*)d_in[8];
  const float* n3g = (const float*)d_in[9];  const float* n3b = (const float*)d_in[10];
  const float* fng = (const float*)d_in[11]; const float* fnb = (const float*)d_in[12];
  const float* w1  = (const float*)d_in[13]; const float* b1  = (const float*)d_in[14];
  const float* w2  = (const float*)d_in[15];
  const float* fw  = (const float*)d_in[16];
  const float* qw  = (const float*)d_in[17]; const float* qbi  = (const float*)d_in[18];
  const float* kvw = (const float*)d_in[19]; const float* kvbi = (const float*)d_in[20];
  const float* ow  = (const float*)d_in[21]; const float* obi  = (const float*)d_in[22];
  const float* d3n1g = (const float*)d_in[23]; const float* d3n1b = (const float*)d_in[24];
  const float* d3w1  = (const float*)d_in[25]; const float* d3b1  = (const float*)d_in[26];
  const float* d3fng = (const float*)d_in[27]; const float* d3fnb = (const float*)d_in[28];
  const float* d3w2  = (const float*)d_in[29];
  const float* ang   = (const float*)d_in[30]; const float* anb = (const float*)d_in[31];
  const float* outw  = (const float*)d_in[32]; const float* outb = (const float*)d_in[33];

  // d_out scratch (proven layout); keys/vals regions overwritten at the end
  float* sc  = out_keys;
  float* ov  = out_vals;
  float* lf  = ov + 0;
  float* y1  = ov + 32768;
  float* y4  = ov + 98304;
  float* xb  = ov + 131072;
  float* y2  = ov + 360448;
  float* qp  = ov + 491520;
  float* rs  = ov + 753920;
  float* lg  = ov + 754176;
  // d_ws: split-K partials (ctx partials in [0, pz_ctx*4); oproj at +524288)
  float* wsf   = (float*)d_ws;
  float* part  = wsf;
  float* part2 = wsf + 524288;    // oproj/w1/w2/qproj partials (<= 524288 floats)
  float* partE = wsf + 1048576;
  float* partN = wsf + 2097152;

  const float alpha = 0.08838834764831845f;
  const long TH = (long)TT * HID;
  const long pz_ctx = (long)(ncho + 4) * 64 * DKH;

  redln_k<<<TT, 256, 0, stream>>>(lfrm, HID, 1, nullptr, nullptr, 0,
                                  n1g, n1b, lf, y1);

  for (int l = 0; l < LAY; ++l) {
    const float* Wkv = kvw + (size_t)l * HID * 2 * HID;
    const float* Bkv = kvbi + (size_t)l * 2 * HID;
    const float* qbi_l = qbi + (size_t)l * HID;
    // ---- FFN: w1 splitK8 (32-wide tiles, 512 blocks) -> redln -> y2 ----
    gemm32_nn<<<dim3(64, 8, 1), 256, 0, stream>>>(
        y1, HID, 0, w1 + (size_t)l * HID * FF, FF, 0, FF, HID, 8, part2, 0, 0,
        1, 0, nullptr, nullptr, 0);
    redln_k<<<TT, 256, 0, stream>>>(part2, FF, 8, b1 + (size_t)l * FF, nullptr, 1,
                                    fng + (size_t)l * FF, fnb + (size_t)l * FF,
                                    nullptr, y2);
    // ---- w2 splitK32 (32-wide tiles, 512 blocks) -> redln -> y4 ----
    gemm32_nn<<<dim3(16, 32, 1), 256, 0, stream>>>(
        y2, FF, 0, w2 + (size_t)l * FF * HID, HID, 0, HID, FF, 32, part2, 0, 0,
        1, 0, nullptr, nullptr, 0);
    redln_k<<<TT, 256, 0, stream>>>(part2, HID, 32, nullptr, nullptr, 0,
                                    n2g + l * HID, n2b + l * HID, nullptr, y4);
    // ---- FSMN + LN3 ----
    fsmnln_k<<<TT, 256, 0, stream>>>(y4, lf, fcache + (size_t)l * HID * (KW - 1),
                                     fw + (size_t)l * HID * KW,
                                     n3g + l * HID, n3b + l * HID,
                                     xb, out_fsmn + (size_t)l * HID * (KW - 1 + TT), y1);
    // ---- Q projection splitK8 (32-wide tiles, 128 blocks) -> part2 ----
    gemm32_nn<<<dim3(16, 8, 1), 256, 0, stream>>>(
        y1, HID, 0, qw + (size_t)l * HID * HID, HID, 0, HID, HID, 8, part2, 0, 0,
        1, 0, nullptr, nullptr, 0);
    // ---- merged qp + scores-old (A = summed q partials) ----
    attn1_k<<<dim3(8 + ckv / 64, 1, NHD), 256, 0, stream>>>(
        part2, qbi_l, Wkv, kcache + (size_t)l * NHD * DKH * ckv, qp, sc, ckv, sct);
    // ---- scores-new = qp @ enc^T (splitK2; chunk1 -> partN) ----
    gemm_nt<<<dim3(32, 2, NHD), 256, 0, stream>>>(
        qp, HID, TH, enc, HID, 0, sc + ckv, sct, TS, SEQ, HID, 2, partN);
    // ---- softmax (fused qc-dot + partN sum; reads q partials in part2) ----
    softmax_k<<<NHD * TT, 256, 0, stream>>>(sc, rs, part2, qbi_l, Bkv, partN,
                                            sct, ckv, alpha);
    // ---- merged ctx-old (split ncho) + ctxE (split 8) partials -> part ----
    attn2_k<<<dim3(10, 8, NHD), 256, 0, stream>>>(
        sc, vcache + (size_t)l * NHD * ckv * DKH, enc, part, partE,
        ckv, sct, ncho, pz_ctx);
    // ---- ceWv: fused 8-chunk A-sum, splitK4 -> ctx partials (coff=ncho) ----
    gemm32_nn<<<dim3(4, 4, NHD), 256, 0, stream>>>(
        partE, HID, 8L * 64 * HID, Wkv + HID, 2 * HID, DKH, DKH, HID, 4,
        part, pz_ctx, ncho, 8, 64L * HID, nullptr, nullptr, 0);
    // ---- oproj: ctx-mode A-load (folds old red_k: chunk-sum + rs*bias_v) ---
    gemm32_nn<<<dim3(16, 8, 1), 256, 0, stream>>>(
        part, 0, 0, ow + (size_t)l * HID * HID, HID, 0, HID, HID, 8, part2, 0, 0,
        ncho + 4, 8192, rs, Bkv + HID, pz_ctx);
    const float* ng = (l + 1 < LAY) ? n1g + (l + 1) * HID : d3n1g;
    const float* nb = (l + 1 < LAY) ? n1b + (l + 1) * HID : d3n1b;
    redln_k<<<TT, 256, 0, stream>>>(part2, HID, 8, obi + (size_t)l * HID, xb, 0,
                                    ng, nb, lf, y1);
  }

  // ---- final decoder3 block + vocab + argmax ----
  gemm32_nn<<<dim3(64, 8, 1), 256, 0, stream>>>(
      y1, HID, 0, d3w1, FF, 0, FF, HID, 8, part2, 0, 0, 1, 0, nullptr, nullptr, 0);
  redln_k<<<TT, 256, 0, stream>>>(part2, FF, 8, d3b1, nullptr, 1,
                                  d3fng, d3fnb, nullptr, y2);
  gemm32_nn<<<dim3(16, 32, 1), 256, 0, stream>>>(
      y2, FF, 0, d3w2, HID, 0, HID, FF, 32, part2, 0, 0, 1, 0, nullptr, nullptr, 0);
  redln_k<<<TT, 256, 0, stream>>>(part2, HID, 32, nullptr, nullptr, 0,
                                  ang, anb, nullptr, y4);
  gemm_nn<<<dim3((VOC + 63) / 64, 1, 1), 256, 0, stream>>>(
      y4, HID, 0, outw, VOC, 0, lg, VOC, 0, outb, nullptr, 0,
      VOC, HID, 0, 1, nullptr, 0, 0, 1, 0);
  argmax_k<<<TT, 256, 0, stream>>>(lg, out_ids);

  // ---- LAST: overwrite scratch regions with real save_keys / save_values ---
  kvsave_k<<<dim3(2 * HID / 64, LBN / 64, LAY), 256, 0, stream>>>(
      enc, kvw, kvbi, out_keys, out_vals);
}